// Round 4
// baseline (5162.674 us; speedup 1.0000x reference)
//
#include <hip/hip_runtime.h>
#include <hip/hip_fp16.h>

#define BB 8
#define SS 2048
#define EE 1024
#define NHH 4
#define DHH 256

__device__ __forceinline__ __half2 u2h2(unsigned int u) {
  union { unsigned int u; __half2 h; } c; c.u = u; return c.h;
}
__device__ __forceinline__ unsigned int h2u(__half2 h) {
  union { unsigned int u; __half2 h; } c; c.h = h; return c.u;
}

// ---------------------------------------------------------------------------
// Gates projection GEMM, conv+SiLU fused into A-staging for pair 0.
// grid (256 m-tiles, 8 n-tiles, 8 problems), block 256.
// Output: gx f16, layout [S][B][NH][4*DH] = [i(256) f(256) z(256) o(256)]
// ---------------------------------------------------------------------------
__global__ __launch_bounds__(256) void gates_gemm(
    const float* __restrict__ x, const float* __restrict__ conv_w,
    const float* __restrict__ conv_b,
    const float* __restrict__ fgw, const float* __restrict__ igw,
    const float* __restrict__ zgw, const float* __restrict__ ogw,
    __half* __restrict__ gx)
{
  __shared__ float Xs[67][33];
  __shared__ float As[64][33];
  __shared__ float Bs[32][68];

  const int tid = threadIdx.x;
  const int mt = blockIdx.x;           // 0..255
  const int nt = blockIdx.y;           // 0..7
  const int p  = blockIdx.z;           // 0..7
  const int h  = p >> 1, pair = p & 1;
  const int b  = mt >> 5;
  const int s0 = (mt & 31) << 6;
  const int n0 = nt << 6;

  const float* W0 = pair ? zgw : fgw;
  const float* W1 = pair ? ogw : igw;

  const int tx = tid & 15, ty = tid >> 4;
  float acc[4][4] = {};

  for (int d0 = 0; d0 < DHH; d0 += 32) {
    for (int i = tid; i < 67 * 32; i += 256) {
      int r = i >> 5, c = i & 31;
      int s = s0 - 3 + r;
      float v = 0.f;
      if (s >= 0) v = x[((size_t)b * SS + s) * EE + h * DHH + d0 + c];
      Xs[r][c] = v;
    }
    for (int i = tid; i < 32 * 64; i += 256) {
      int j = i >> 5, c = i & 31;
      int o = n0 + j;
      const float* Wp = (o < 256) ? W0 : W1;
      int oo = o & 255;
      Bs[c][j] = Wp[((size_t)h * DHH + oo) * DHH + d0 + c];
    }
    __syncthreads();
    if (pair == 0) {
      for (int i = tid; i < 64 * 32; i += 256) {
        int r = i >> 5, c = i & 31;
        int e = h * DHH + d0 + c;
        float xc = conv_b[e];
        xc = fmaf(Xs[r + 0][c], conv_w[0 * EE + e], xc);
        xc = fmaf(Xs[r + 1][c], conv_w[1 * EE + e], xc);
        xc = fmaf(Xs[r + 2][c], conv_w[2 * EE + e], xc);
        xc = fmaf(Xs[r + 3][c], conv_w[3 * EE + e], xc);
        float sg = 1.f / (1.f + __expf(-xc));
        As[r][c] = xc * sg;
      }
    } else {
      for (int i = tid; i < 64 * 32; i += 256) {
        int r = i >> 5, c = i & 31;
        As[r][c] = Xs[r + 3][c];
      }
    }
    __syncthreads();
#pragma unroll
    for (int kk = 0; kk < 32; ++kk) {
      float a[4];
#pragma unroll
      for (int i = 0; i < 4; ++i) a[i] = As[ty * 4 + i][kk];
      float4 bv = *(const float4*)&Bs[kk][tx * 4];
      float bb[4] = {bv.x, bv.y, bv.z, bv.w};
#pragma unroll
      for (int i = 0; i < 4; ++i)
#pragma unroll
        for (int j = 0; j < 4; ++j)
          acc[i][j] = fmaf(a[i], bb[j], acc[i][j]);
    }
    __syncthreads();
  }

#pragma unroll
  for (int i = 0; i < 4; ++i) {
    int s = s0 + ty * 4 + i;
    size_t base = (((size_t)s * BB + b) * NHH + h) * 1024 + (size_t)pair * 512 + n0 + tx * 4;
    uint2 st;
    st.x = h2u(__floats2half2_rn(acc[i][0], acc[i][1]));
    st.y = h2u(__floats2half2_rn(acc[i][2], acc[i][3]));
    *(uint2*)(gx + base) = st;
  }
}

// ---------------------------------------------------------------------------
// sLSTM scan: one workgroup (512 threads) per chain (b,h).
// Thread pair (2d, 2d+1) owns dim d; even lane: cols d (i), 512+d (z);
// odd lane: cols 256+d (f), 768+d (o).
// Weights: col k0 in VGPR (128 half2); col k1: 64 half2 VGPR + 64 half2 LDS.
// y: per-lane-distinct ds_read_b64 (lane l holds half2 pair 2l,2l+1), then
// readlane->SGPR broadcast consumed directly by v_pk_fma_f16.
// One barrier per step. Dynamic LDS: 131072 (wl) + 1024 (ypub x2) = 132096 B
// ---------------------------------------------------------------------------
__global__ __launch_bounds__(512)
__attribute__((amdgpu_waves_per_eu(2, 2)))
void slstm_scan(
    const float* __restrict__ rk,    // (NH, DH, 4*DH)
    const float* __restrict__ rb,    // (NH, 4, DH)
    const __half* __restrict__ gx,   // [S][B][NH][1024]
    float* __restrict__ out)         // (B, S, E)
{
  extern __shared__ unsigned char smem[];
  uint2* wl    = (uint2*)smem;                      // [32][512]
  __half* ypub = (__half*)(smem + 131072);          // [2][256]

  const int t = threadIdx.x;
  const int lane = t & 63;
  const int b = blockIdx.x >> 2, h = blockIdx.x & 3;
  const int d = t >> 1, par = t & 1;
  const int k0 = par * 256 + d;
  const int k1 = 512 + par * 256 + d;
  const float* Rh = rk + (size_t)h * DHH * 1024;

  __half2 w0[128];
  __half2 w1r[64];
#pragma unroll
  for (int pp = 0; pp < 128; ++pp)
    w0[pp] = __floats2half2_rn(Rh[(2 * pp) * 1024 + k0], Rh[(2 * pp + 1) * 1024 + k0]);
#pragma unroll
  for (int pp = 0; pp < 64; ++pp)
    w1r[pp] = __floats2half2_rn(Rh[(2 * pp) * 1024 + k1], Rh[(2 * pp + 1) * 1024 + k1]);
  for (int q = 0; q < 32; ++q) {
    // entry q of wl = col-k1 half2s for k = 64+2q, 65+2q (y elems 128+4q..131+4q)
    __half2 pa = __floats2half2_rn(Rh[(128 + 4 * q + 0) * 1024 + k1],
                                   Rh[(128 + 4 * q + 1) * 1024 + k1]);
    __half2 pb = __floats2half2_rn(Rh[(128 + 4 * q + 2) * 1024 + k1],
                                   Rh[(128 + 4 * q + 3) * 1024 + k1]);
    uint2 u; u.x = h2u(pa); u.y = h2u(pb);
    wl[q * 512 + t] = u;
  }
  const float rb0 = rb[h * 1024 + k0];
  const float rb1 = rb[h * 1024 + k1];
  float c = 0.f, n = 0.f, m = 0.f;
  if (t < 256) ypub[t] = __float2half(0.f);
  if (t < 256) ypub[256 + t] = __float2half(0.f);
  __syncthreads();

  int cur = 0;
  const __half* pg = gx + ((size_t)b * NHH + h) * 1024;
  float cx0 = __half2float(pg[k0]);
  float cx1 = __half2float(pg[k1]);
  const __half2 hz = __floats2half2_rn(0.f, 0.f);
  const size_t out_base = ((size_t)b * SS) * EE + h * DHH + d;

  for (int st = 0; st < SS; ++st) {
    // prefetch next step's gate inputs
    const __half* pn = pg + ((st + 1 < SS) ? (size_t)(BB * NHH * 1024) : 0);
    const __half nx0 = pn[k0];
    const __half nx1 = pn[k1];

    // whole y(t) into the wave: lane l holds half2 pair (2l, 2l+1)
    const uint2 yl = *(const uint2*)((const unsigned int*)(ypub + cur * 256) + 2 * lane);

    __half2 a0 = hz, a1 = hz;
    // k = 0..63: both cols' weights in VGPR. y half2 k=2mm (+1) lives in lane mm.
#pragma unroll
    for (int mm = 0; mm < 32; ++mm) {
      unsigned se = (unsigned)__builtin_amdgcn_readlane((int)yl.x, mm);
      unsigned so = (unsigned)__builtin_amdgcn_readlane((int)yl.y, mm);
      __half2 ye = u2h2(se), yo = u2h2(so);
      a0 = __hfma2(w0[2 * mm + 0], ye, a0);
      a1 = __hfma2(w1r[2 * mm + 0], ye, a1);
      a0 = __hfma2(w0[2 * mm + 1], yo, a0);
      a1 = __hfma2(w1r[2 * mm + 1], yo, a1);
    }
    // k = 64..127: col-k1 weights from LDS (per-lane-distinct b64 reads)
#pragma unroll
    for (int q = 0; q < 32; ++q) {
      uint2 wq = wl[q * 512 + t];
      unsigned se = (unsigned)__builtin_amdgcn_readlane((int)yl.x, 32 + q);
      unsigned so = (unsigned)__builtin_amdgcn_readlane((int)yl.y, 32 + q);
      __half2 ye = u2h2(se), yo = u2h2(so);
      a0 = __hfma2(w0[64 + 2 * q + 0], ye, a0);
      a1 = __hfma2(u2h2(wq.x), ye, a1);
      a0 = __hfma2(w0[64 + 2 * q + 1], yo, a0);
      a1 = __hfma2(u2h2(wq.y), yo, a1);
    }

    float acc0 = __low2float(a0) + __high2float(a0);
    float acc1 = __low2float(a1) + __high2float(a1);
    float raw0 = acc0 + cx0 + rb0;
    float raw1 = acc1 + cx1 + rb1;

    // in-wave exchange with partner lane (even<->odd)
    float pr0 = __shfl_xor(raw0, 1);
    float pr1 = __shfl_xor(raw1, 1);
    float iv = par ? pr0 : raw0;
    float fv = par ? raw0 : pr0;
    float zv = par ? pr1 : raw1;
    float ov = par ? raw1 : pr1;

    // state update (redundant in both lanes of the pair)
    float ea = __expf(-fabsf(fv));
    float ls = fminf(fv, 0.f) - __logf(1.f + ea);      // log_sigmoid(fv)
    float lfm = m + ls;
    float mn = fmaxf(iv, lfm);
    float ig = __expf(iv - mn);
    float fg = __expf(lfm - mn);
    float pz = __expf(-2.f * fabsf(zv));
    float tmag = __fdividef(1.f - pz, 1.f + pz);
    float th = (zv < 0.f) ? -tmag : tmag;              // tanh(zv)
    c = fg * c + ig * th;
    n = fg * n + ig;
    float og = __fdividef(1.f, 1.f + __expf(-ov));     // sigmoid(ov)
    float y = og * __fdividef(c, n);
    m = mn;

    if (par == 0) {
      out[out_base + (size_t)st * EE] = y;
      ypub[(cur ^ 1) * 256 + d] = __float2half(y);
    }
    __syncthreads();
    cur ^= 1;
    pg = pn;
    cx0 = __half2float(nx0);
    cx1 = __half2float(nx1);
  }
}

// ---------------------------------------------------------------------------
// GroupNorm over DH per (b,s,h), in place on out. One wave = one head.
// ---------------------------------------------------------------------------
__global__ __launch_bounds__(256) void groupnorm(
    float* __restrict__ y, const float* __restrict__ gnw)
{
  const int row = blockIdx.x;
  const int t = threadIdx.x;
  float4 v = ((const float4*)y)[(size_t)row * 256 + t];
  float s = v.x + v.y + v.z + v.w;
  float q = v.x * v.x + v.y * v.y + v.z * v.z + v.w * v.w;
#pragma unroll
  for (int mask = 1; mask < 64; mask <<= 1) {
    s += __shfl_xor(s, mask, 64);
    q += __shfl_xor(q, mask, 64);
  }
  float mu = s * (1.f / 256.f);
  float var = q * (1.f / 256.f) - mu * mu;
  float rs = rsqrtf(var + 1e-5f);
  float4 g = ((const float4*)gnw)[t];
  float4 o;
  o.x = (v.x - mu) * rs * g.x;
  o.y = (v.y - mu) * rs * g.y;
  o.z = (v.z - mu) * rs * g.z;
  o.w = (v.w - mu) * rs * g.w;
  ((float4*)y)[(size_t)row * 256 + t] = o;
}

extern "C" void kernel_launch(void* const* d_in, const int* in_sizes, int n_in,
                              void* d_out, int out_size, void* d_ws, size_t ws_size,
                              hipStream_t stream) {
  const float* x      = (const float*)d_in[0];
  const float* conv_w = (const float*)d_in[1];
  const float* conv_b = (const float*)d_in[2];
  const float* fgw    = (const float*)d_in[3];
  const float* igw    = (const float*)d_in[4];
  const float* zgw    = (const float*)d_in[5];
  const float* ogw    = (const float*)d_in[6];
  const float* rk     = (const float*)d_in[7];
  const float* rb     = (const float*)d_in[8];
  const float* gnw    = (const float*)d_in[9];
  float* out = (float*)d_out;
  __half* gx = (__half*)d_ws;   // [S][B][NH][1024] f16 = 134217728 B

  dim3 g1(256, 8, 8);
  gates_gemm<<<g1, 256, 0, stream>>>(x, conv_w, conv_b, fgw, igw, zgw, ogw, gx);

  const int scan_lds = 131072 + 1024;
  (void)hipFuncSetAttribute(reinterpret_cast<const void*>(slstm_scan),
                            hipFuncAttributeMaxDynamicSharedMemorySize, scan_lds);
  slstm_scan<<<32, 512, scan_lds, stream>>>(rk, rb, gx, out);

  groupnorm<<<BB * SS, 256, 0, stream>>>(out, gnw);
}

// Round 5
// 4415.732 us; speedup vs baseline: 1.1692x; 1.1692x over previous
//
#include <hip/hip_runtime.h>
#include <hip/hip_fp16.h>

#define BB 8
#define SS 2048
#define EE 1024
#define NHH 4
#define DHH 256

__device__ __forceinline__ __half2 u2h2(unsigned int u) {
  union { unsigned int u; __half2 h; } c; c.u = u; return c.h;
}
__device__ __forceinline__ unsigned int h2u(__half2 h) {
  union { unsigned int u; __half2 h; } c; c.h = h; return c.u;
}

// ---------------------------------------------------------------------------
// Gates projection GEMM, conv+SiLU fused into A-staging for pair 0.
// grid (256 m-tiles, 8 n-tiles, 8 problems), block 256.
// Output: gx f16, layout [S][B][NH][4*DH] = [i(256) f(256) z(256) o(256)]
// ---------------------------------------------------------------------------
__global__ __launch_bounds__(256) void gates_gemm(
    const float* __restrict__ x, const float* __restrict__ conv_w,
    const float* __restrict__ conv_b,
    const float* __restrict__ fgw, const float* __restrict__ igw,
    const float* __restrict__ zgw, const float* __restrict__ ogw,
    __half* __restrict__ gx)
{
  __shared__ float Xs[67][33];
  __shared__ float As[64][33];
  __shared__ float Bs[32][68];

  const int tid = threadIdx.x;
  const int mt = blockIdx.x;           // 0..255
  const int nt = blockIdx.y;           // 0..7
  const int p  = blockIdx.z;           // 0..7
  const int h  = p >> 1, pair = p & 1;
  const int b  = mt >> 5;
  const int s0 = (mt & 31) << 6;
  const int n0 = nt << 6;

  const float* W0 = pair ? zgw : fgw;
  const float* W1 = pair ? ogw : igw;

  const int tx = tid & 15, ty = tid >> 4;
  float acc[4][4] = {};

  for (int d0 = 0; d0 < DHH; d0 += 32) {
    for (int i = tid; i < 67 * 32; i += 256) {
      int r = i >> 5, c = i & 31;
      int s = s0 - 3 + r;
      float v = 0.f;
      if (s >= 0) v = x[((size_t)b * SS + s) * EE + h * DHH + d0 + c];
      Xs[r][c] = v;
    }
    for (int i = tid; i < 32 * 64; i += 256) {
      int j = i >> 5, c = i & 31;
      int o = n0 + j;
      const float* Wp = (o < 256) ? W0 : W1;
      int oo = o & 255;
      Bs[c][j] = Wp[((size_t)h * DHH + oo) * DHH + d0 + c];
    }
    __syncthreads();
    if (pair == 0) {
      for (int i = tid; i < 64 * 32; i += 256) {
        int r = i >> 5, c = i & 31;
        int e = h * DHH + d0 + c;
        float xc = conv_b[e];
        xc = fmaf(Xs[r + 0][c], conv_w[0 * EE + e], xc);
        xc = fmaf(Xs[r + 1][c], conv_w[1 * EE + e], xc);
        xc = fmaf(Xs[r + 2][c], conv_w[2 * EE + e], xc);
        xc = fmaf(Xs[r + 3][c], conv_w[3 * EE + e], xc);
        float sg = 1.f / (1.f + __expf(-xc));
        As[r][c] = xc * sg;
      }
    } else {
      for (int i = tid; i < 64 * 32; i += 256) {
        int r = i >> 5, c = i & 31;
        As[r][c] = Xs[r + 3][c];
      }
    }
    __syncthreads();
#pragma unroll
    for (int kk = 0; kk < 32; ++kk) {
      float a[4];
#pragma unroll
      for (int i = 0; i < 4; ++i) a[i] = As[ty * 4 + i][kk];
      float4 bv = *(const float4*)&Bs[kk][tx * 4];
      float bb[4] = {bv.x, bv.y, bv.z, bv.w};
#pragma unroll
      for (int i = 0; i < 4; ++i)
#pragma unroll
        for (int j = 0; j < 4; ++j)
          acc[i][j] = fmaf(a[i], bb[j], acc[i][j]);
    }
    __syncthreads();
  }

#pragma unroll
  for (int i = 0; i < 4; ++i) {
    int s = s0 + ty * 4 + i;
    size_t base = (((size_t)s * BB + b) * NHH + h) * 1024 + (size_t)pair * 512 + n0 + tx * 4;
    uint2 st;
    st.x = h2u(__floats2half2_rn(acc[i][0], acc[i][1]));
    st.y = h2u(__floats2half2_rn(acc[i][2], acc[i][3]));
    *(uint2*)(gx + base) = st;
  }
}

// ---------------------------------------------------------------------------
// sLSTM scan: one workgroup (512 threads) per chain (b,h).
// Thread pair (2d, 2d+1) owns dim d; even lane: cols d (i), 512+d (z);
// odd lane: cols 256+d (f), 768+d (o).
// Weights: col k0 fully in VGPR (128 half2); col k1: 64 half2 VGPR + 64
// half2 in LDS packed as uint4 (16 x ds_read_b128 per step).
// y double-buffered in LDS (f16), broadcast uint4 reads.
// One barrier per step; gate exchange via in-wave __shfl_xor(.,1).
// amdgpu_waves_per_eu(1): per-wave VGPR budget 512 -> arch cap 256, so the
// 192 weight half2s live in arch VGPRs (no accvgpr move tax).
// Dynamic LDS: 131072 (wl4) + 1024 (ypub x2) = 132096 B
// ---------------------------------------------------------------------------
__global__
__attribute__((amdgpu_flat_work_group_size(512, 512), amdgpu_waves_per_eu(1)))
void slstm_scan(
    const float* __restrict__ rk,    // (NH, DH, 4*DH)
    const float* __restrict__ rb,    // (NH, 4, DH)
    const __half* __restrict__ gx,   // [S][B][NH][1024]
    float* __restrict__ out)         // (B, S, E)
{
  extern __shared__ unsigned char smem[];
  uint4* wl4   = (uint4*)smem;                      // [16][512]
  __half* ypub = (__half*)(smem + 131072);          // [2][256]

  const int t = threadIdx.x;
  const int b = blockIdx.x >> 2, h = blockIdx.x & 3;
  const int d = t >> 1, par = t & 1;
  const int k0 = par * 256 + d;
  const int k1 = 512 + par * 256 + d;
  const float* Rh = rk + (size_t)h * DHH * 1024;

  __half2 w0[128];
  __half2 w1r[64];
#pragma unroll
  for (int pp = 0; pp < 128; ++pp)
    w0[pp] = __floats2half2_rn(Rh[(2 * pp) * 1024 + k0], Rh[(2 * pp + 1) * 1024 + k0]);
#pragma unroll
  for (int pp = 0; pp < 64; ++pp)
    w1r[pp] = __floats2half2_rn(Rh[(2 * pp) * 1024 + k1], Rh[(2 * pp + 1) * 1024 + k1]);
  for (int q = 0; q < 16; ++q) {
    // entry q of wl4 = col-k1 half2 pairs (64+4q .. 67+4q)
    uint4 u;
    u.x = h2u(__floats2half2_rn(Rh[(128 + 8 * q + 0) * 1024 + k1],
                                Rh[(128 + 8 * q + 1) * 1024 + k1]));
    u.y = h2u(__floats2half2_rn(Rh[(128 + 8 * q + 2) * 1024 + k1],
                                Rh[(128 + 8 * q + 3) * 1024 + k1]));
    u.z = h2u(__floats2half2_rn(Rh[(128 + 8 * q + 4) * 1024 + k1],
                                Rh[(128 + 8 * q + 5) * 1024 + k1]));
    u.w = h2u(__floats2half2_rn(Rh[(128 + 8 * q + 6) * 1024 + k1],
                                Rh[(128 + 8 * q + 7) * 1024 + k1]));
    wl4[q * 512 + t] = u;
  }
  const float rb0 = rb[h * 1024 + k0];
  const float rb1 = rb[h * 1024 + k1];
  float c = 0.f, n = 0.f, m = 0.f;
  if (t < 256) { ypub[t] = __float2half(0.f); ypub[256 + t] = __float2half(0.f); }
  __syncthreads();

  int cur = 0;
  const __half* pg = gx + ((size_t)b * NHH + h) * 1024;
  float cx0 = __half2float(pg[k0]);
  float cx1 = __half2float(pg[k1]);
  const __half2 hz = __floats2half2_rn(0.f, 0.f);
  const size_t out_base = ((size_t)b * SS) * EE + h * DHH + d;

  for (int st = 0; st < SS; ++st) {
    // prefetch next step's gate inputs
    const __half* pn = pg + ((st + 1 < SS) ? (size_t)(BB * NHH * 1024) : 0);
    const __half nx0 = pn[k0];
    const __half nx1 = pn[k1];

    const uint4* yv = (const uint4*)(ypub + cur * 256);
    __half2 s0a = hz, s0b = hz, s1a = hz, s1b = hz;
    // k-dims 0..127: both cols' weights in VGPR
#pragma unroll
    for (int j = 0; j < 16; ++j) {
      uint4 yq = yv[j];   // y half2 pairs 4j..4j+3 (broadcast read)
      __half2 y0 = u2h2(yq.x), y1 = u2h2(yq.y), y2 = u2h2(yq.z), y3 = u2h2(yq.w);
      s0a = __hfma2(w0[4 * j + 0], y0, s0a);
      s1a = __hfma2(w1r[4 * j + 0], y0, s1a);
      s0b = __hfma2(w0[4 * j + 1], y1, s0b);
      s1b = __hfma2(w1r[4 * j + 1], y1, s1b);
      s0a = __hfma2(w0[4 * j + 2], y2, s0a);
      s1a = __hfma2(w1r[4 * j + 2], y2, s1a);
      s0b = __hfma2(w0[4 * j + 3], y3, s0b);
      s1b = __hfma2(w1r[4 * j + 3], y3, s1b);
    }
    // k-dims 128..255: col-k1 weights stream from LDS (b128, per-lane)
#pragma unroll
    for (int j = 16; j < 32; ++j) {
      uint4 yq = yv[j];
      uint4 wq = wl4[(j - 16) * 512 + t];   // col-k1 half2 pairs 4j..4j+3
      __half2 y0 = u2h2(yq.x), y1 = u2h2(yq.y), y2 = u2h2(yq.z), y3 = u2h2(yq.w);
      s0a = __hfma2(w0[4 * j + 0], y0, s0a);
      s1a = __hfma2(u2h2(wq.x), y0, s1a);
      s0b = __hfma2(w0[4 * j + 1], y1, s0b);
      s1b = __hfma2(u2h2(wq.y), y1, s1b);
      s0a = __hfma2(w0[4 * j + 2], y2, s0a);
      s1a = __hfma2(u2h2(wq.z), y2, s1a);
      s0b = __hfma2(w0[4 * j + 3], y3, s0b);
      s1b = __hfma2(u2h2(wq.w), y3, s1b);
    }

    float acc0 = __low2float(s0a) + __high2float(s0a) + __low2float(s0b) + __high2float(s0b);
    float acc1 = __low2float(s1a) + __high2float(s1a) + __low2float(s1b) + __high2float(s1b);
    float raw0 = acc0 + cx0 + rb0;
    float raw1 = acc1 + cx1 + rb1;

    // in-wave exchange with partner lane (even<->odd)
    float pr0 = __shfl_xor(raw0, 1);
    float pr1 = __shfl_xor(raw1, 1);
    float iv = par ? pr0 : raw0;
    float fv = par ? raw0 : pr0;
    float zv = par ? pr1 : raw1;
    float ov = par ? raw1 : pr1;

    // state update (redundant in both lanes of the pair)
    float ea = __expf(-fabsf(fv));
    float ls = fminf(fv, 0.f) - __logf(1.f + ea);      // log_sigmoid(fv)
    float lfm = m + ls;
    float mn = fmaxf(iv, lfm);
    float ig = __expf(iv - mn);
    float fg = __expf(lfm - mn);
    float pz = __expf(-2.f * fabsf(zv));
    float tmag = __fdividef(1.f - pz, 1.f + pz);
    float th = (zv < 0.f) ? -tmag : tmag;              // tanh(zv)
    c = fg * c + ig * th;
    n = fg * n + ig;
    float og = __fdividef(1.f, 1.f + __expf(-ov));     // sigmoid(ov)
    float y = og * __fdividef(c, n);
    m = mn;

    if (par == 0) {
      out[out_base + (size_t)st * EE] = y;
      ypub[(cur ^ 1) * 256 + d] = __float2half(y);
    }
    __syncthreads();
    cur ^= 1;
    pg = pn;
    cx0 = __half2float(nx0);
    cx1 = __half2float(nx1);
  }
}

// ---------------------------------------------------------------------------
// GroupNorm over DH per (b,s,h), in place on out. One wave = one head.
// ---------------------------------------------------------------------------
__global__ __launch_bounds__(256) void groupnorm(
    float* __restrict__ y, const float* __restrict__ gnw)
{
  const int row = blockIdx.x;
  const int t = threadIdx.x;
  float4 v = ((const float4*)y)[(size_t)row * 256 + t];
  float s = v.x + v.y + v.z + v.w;
  float q = v.x * v.x + v.y * v.y + v.z * v.z + v.w * v.w;
#pragma unroll
  for (int mask = 1; mask < 64; mask <<= 1) {
    s += __shfl_xor(s, mask, 64);
    q += __shfl_xor(q, mask, 64);
  }
  float mu = s * (1.f / 256.f);
  float var = q * (1.f / 256.f) - mu * mu;
  float rs = rsqrtf(var + 1e-5f);
  float4 g = ((const float4*)gnw)[t];
  float4 o;
  o.x = (v.x - mu) * rs * g.x;
  o.y = (v.y - mu) * rs * g.y;
  o.z = (v.z - mu) * rs * g.z;
  o.w = (v.w - mu) * rs * g.w;
  ((float4*)y)[(size_t)row * 256 + t] = o;
}

extern "C" void kernel_launch(void* const* d_in, const int* in_sizes, int n_in,
                              void* d_out, int out_size, void* d_ws, size_t ws_size,
                              hipStream_t stream) {
  const float* x      = (const float*)d_in[0];
  const float* conv_w = (const float*)d_in[1];
  const float* conv_b = (const float*)d_in[2];
  const float* fgw    = (const float*)d_in[3];
  const float* igw    = (const float*)d_in[4];
  const float* zgw    = (const float*)d_in[5];
  const float* ogw    = (const float*)d_in[6];
  const float* rk     = (const float*)d_in[7];
  const float* rb     = (const float*)d_in[8];
  const float* gnw    = (const float*)d_in[9];
  float* out = (float*)d_out;
  __half* gx = (__half*)d_ws;   // [S][B][NH][1024] f16 = 134217728 B

  dim3 g1(256, 8, 8);
  gates_gemm<<<g1, 256, 0, stream>>>(x, conv_w, conv_b, fgw, igw, zgw, ogw, gx);

  const int scan_lds = 131072 + 1024;
  (void)hipFuncSetAttribute(reinterpret_cast<const void*>(slstm_scan),
                            hipFuncAttributeMaxDynamicSharedMemorySize, scan_lds);
  slstm_scan<<<32, 512, scan_lds, stream>>>(rk, rb, gx, out);

  groupnorm<<<BB * SS, 256, 0, stream>>>(out, gnw);
}

// Round 6
// 4291.762 us; speedup vs baseline: 1.2029x; 1.0289x over previous
//
#include <hip/hip_runtime.h>
#include <hip/hip_fp16.h>

#define BB 8
#define SS 2048
#define EE 1024
#define NHH 4
#define DHH 256

typedef _Float16 f16x2 __attribute__((ext_vector_type(2)));

__device__ __forceinline__ __half2 u2h2(unsigned int u) {
  union { unsigned int u; __half2 h; } c; c.u = u; return c.h;
}
__device__ __forceinline__ unsigned int h2u(__half2 h) {
  union { unsigned int u; __half2 h; } c; c.h = h; return c.u;
}
__device__ __forceinline__ f16x2 u2f(unsigned int u) {
  union { unsigned int u; f16x2 f; } c; c.u = u; return c.f;
}
__device__ __forceinline__ unsigned int pack2(float a, float b) {
  f16x2 f; f.x = (_Float16)a; f.y = (_Float16)b;
  union { f16x2 f; unsigned int u; } c; c.f = f; return c.u;
}
__device__ __forceinline__ float fdot2u(unsigned int w, unsigned int y, float acc) {
#if __has_builtin(__builtin_amdgcn_fdot2)
  return __builtin_amdgcn_fdot2(u2f(w), u2f(y), acc, false);
#else
  __half2 a = u2h2(w), b = u2h2(y);
  return acc + __low2float(a) * __low2float(b) + __high2float(a) * __high2float(b);
#endif
}

// ---------------------------------------------------------------------------
// Gates projection GEMM, conv+SiLU fused into A-staging for pair 0.
// grid (256 m-tiles, 8 n-tiles, 8 problems), block 256.
// Output: gx f16, layout [S][B][NH][4*DH] = [i(256) f(256) z(256) o(256)]
// ---------------------------------------------------------------------------
__global__ __launch_bounds__(256) void gates_gemm(
    const float* __restrict__ x, const float* __restrict__ conv_w,
    const float* __restrict__ conv_b,
    const float* __restrict__ fgw, const float* __restrict__ igw,
    const float* __restrict__ zgw, const float* __restrict__ ogw,
    __half* __restrict__ gx)
{
  __shared__ float Xs[67][33];
  __shared__ float As[64][33];
  __shared__ float Bs[32][68];

  const int tid = threadIdx.x;
  const int mt = blockIdx.x;           // 0..255
  const int nt = blockIdx.y;           // 0..7
  const int p  = blockIdx.z;           // 0..7
  const int h  = p >> 1, pair = p & 1;
  const int b  = mt >> 5;
  const int s0 = (mt & 31) << 6;
  const int n0 = nt << 6;

  const float* W0 = pair ? zgw : fgw;
  const float* W1 = pair ? ogw : igw;

  const int tx = tid & 15, ty = tid >> 4;
  float acc[4][4] = {};

  for (int d0 = 0; d0 < DHH; d0 += 32) {
    for (int i = tid; i < 67 * 32; i += 256) {
      int r = i >> 5, c = i & 31;
      int s = s0 - 3 + r;
      float v = 0.f;
      if (s >= 0) v = x[((size_t)b * SS + s) * EE + h * DHH + d0 + c];
      Xs[r][c] = v;
    }
    for (int i = tid; i < 32 * 64; i += 256) {
      int j = i >> 5, c = i & 31;
      int o = n0 + j;
      const float* Wp = (o < 256) ? W0 : W1;
      int oo = o & 255;
      Bs[c][j] = Wp[((size_t)h * DHH + oo) * DHH + d0 + c];
    }
    __syncthreads();
    if (pair == 0) {
      for (int i = tid; i < 64 * 32; i += 256) {
        int r = i >> 5, c = i & 31;
        int e = h * DHH + d0 + c;
        float xc = conv_b[e];
        xc = fmaf(Xs[r + 0][c], conv_w[0 * EE + e], xc);
        xc = fmaf(Xs[r + 1][c], conv_w[1 * EE + e], xc);
        xc = fmaf(Xs[r + 2][c], conv_w[2 * EE + e], xc);
        xc = fmaf(Xs[r + 3][c], conv_w[3 * EE + e], xc);
        float sg = 1.f / (1.f + __expf(-xc));
        As[r][c] = xc * sg;
      }
    } else {
      for (int i = tid; i < 64 * 32; i += 256) {
        int r = i >> 5, c = i & 31;
        As[r][c] = Xs[r + 3][c];
      }
    }
    __syncthreads();
#pragma unroll
    for (int kk = 0; kk < 32; ++kk) {
      float a[4];
#pragma unroll
      for (int i = 0; i < 4; ++i) a[i] = As[ty * 4 + i][kk];
      float4 bv = *(const float4*)&Bs[kk][tx * 4];
      float bb[4] = {bv.x, bv.y, bv.z, bv.w};
#pragma unroll
      for (int i = 0; i < 4; ++i)
#pragma unroll
        for (int j = 0; j < 4; ++j)
          acc[i][j] = fmaf(a[i], bb[j], acc[i][j]);
    }
    __syncthreads();
  }

#pragma unroll
  for (int i = 0; i < 4; ++i) {
    int s = s0 + ty * 4 + i;
    size_t base = (((size_t)s * BB + b) * NHH + h) * 1024 + (size_t)pair * 512 + n0 + tx * 4;
    uint2 st;
    st.x = h2u(__floats2half2_rn(acc[i][0], acc[i][1]));
    st.y = h2u(__floats2half2_rn(acc[i][2], acc[i][3]));
    *(uint2*)(gx + base) = st;
  }
}

// ---------------------------------------------------------------------------
// sLSTM scan: one workgroup (512 threads) per chain (b,h).
// Lane-pair k-split: lane 2d owns dim d with k in [0,128); lane 2d+1 owns
// dim d with k in [128,256). Each lane computes partial sums of ALL FOUR
// gate columns (i,f,z,o at dim d) over its k-half via v_dot2_f32_f16;
// the pair combines partials with 4 shfl_xor(1) (in-wave, no barrier).
// Weights per lane: gates i,f,z (3 x 64 half2) in registers; gate o
// (64 half2) in LDS as uint4 [16][512]. y double-buffered in LDS f16;
// each lane reads only its k-half (16 x b128, two addrs per wave = free).
// One barrier per step.
// Dynamic LDS: 131072 (wl4) + 1024 (ypub x2) = 132096 B
// ---------------------------------------------------------------------------
__global__
__attribute__((amdgpu_flat_work_group_size(512, 512), amdgpu_waves_per_eu(1)))
void slstm_scan(
    const float* __restrict__ rk,    // (NH, DH, 4*DH)
    const float* __restrict__ rb,    // (NH, 4, DH)
    const __half* __restrict__ gx,   // [S][B][NH][1024]
    float* __restrict__ out)         // (B, S, E)
{
  extern __shared__ unsigned char smem[];
  uint4* wl4   = (uint4*)smem;                      // [16][512]
  __half* ypub = (__half*)(smem + 131072);          // [2][256]

  const int t = threadIdx.x;
  const int b = blockIdx.x >> 2, h = blockIdx.x & 3;
  const int d = t >> 1, par = t & 1;
  const int kbase = par << 7;                       // 0 or 128
  const float* Rh = rk + (size_t)h * DHH * 1024;

  // weights: gates 0..2 (i,f,z) in registers, gate 3 (o) in LDS
  unsigned int wv[3][64];
#pragma unroll
  for (int g = 0; g < 3; ++g) {
    const int col = g * 256 + d;
#pragma unroll
    for (int pp = 0; pp < 64; ++pp) {
      int k = kbase + 2 * pp;
      wv[g][pp] = pack2(Rh[(size_t)k * 1024 + col], Rh[(size_t)(k + 1) * 1024 + col]);
    }
  }
  {
    const int col = 3 * 256 + d;
    for (int q = 0; q < 16; ++q) {
      uint4 u;
      int k = kbase + 8 * q;
      u.x = pack2(Rh[(size_t)(k + 0) * 1024 + col], Rh[(size_t)(k + 1) * 1024 + col]);
      u.y = pack2(Rh[(size_t)(k + 2) * 1024 + col], Rh[(size_t)(k + 3) * 1024 + col]);
      u.z = pack2(Rh[(size_t)(k + 4) * 1024 + col], Rh[(size_t)(k + 5) * 1024 + col]);
      u.w = pack2(Rh[(size_t)(k + 6) * 1024 + col], Rh[(size_t)(k + 7) * 1024 + col]);
      wl4[q * 512 + t] = u;
    }
  }

  float rbv[4];
#pragma unroll
  for (int g = 0; g < 4; ++g) rbv[g] = rb[h * 1024 + g * 256 + d];

  float c = 0.f, n = 0.f, m = 0.f;
  if (t < 256) { ypub[t] = __float2half(0.f); ypub[256 + t] = __float2half(0.f); }
  __syncthreads();

  int cur = 0;
  const __half* pg = gx + ((size_t)b * NHH + h) * 1024;
  float cx[4];
#pragma unroll
  for (int g = 0; g < 4; ++g) cx[g] = __half2float(pg[g * 256 + d]);
  const size_t out_base = ((size_t)b * SS) * EE + h * DHH + d;

  for (int st = 0; st < SS; ++st) {
    // prefetch next step's gate inputs
    const __half* pn = pg + ((st + 1 < SS) ? (size_t)(BB * NHH * 1024) : 0);
    __half nx[4];
#pragma unroll
    for (int g = 0; g < 4; ++g) nx[g] = pn[g * 256 + d];

    const uint4* yv = (const uint4*)(ypub + cur * 256) + (par << 4);
    float aA0 = 0.f, aB0 = 0.f, aA1 = 0.f, aB1 = 0.f;
    float aA2 = 0.f, aB2 = 0.f, aA3 = 0.f, aB3 = 0.f;
#pragma unroll
    for (int j = 0; j < 16; ++j) {
      uint4 yq = yv[j];                 // y dims kbase+8j .. kbase+8j+7
      uint4 wq = wl4[j * 512 + t];      // gate-3 weights, same k-range
      aA0 = fdot2u(wv[0][4 * j + 0], yq.x, aA0);
      aA1 = fdot2u(wv[1][4 * j + 0], yq.x, aA1);
      aA2 = fdot2u(wv[2][4 * j + 0], yq.x, aA2);
      aA3 = fdot2u(wq.x,             yq.x, aA3);
      aB0 = fdot2u(wv[0][4 * j + 1], yq.y, aB0);
      aB1 = fdot2u(wv[1][4 * j + 1], yq.y, aB1);
      aB2 = fdot2u(wv[2][4 * j + 1], yq.y, aB2);
      aB3 = fdot2u(wq.y,             yq.y, aB3);
      aA0 = fdot2u(wv[0][4 * j + 2], yq.z, aA0);
      aA1 = fdot2u(wv[1][4 * j + 2], yq.z, aA1);
      aA2 = fdot2u(wv[2][4 * j + 2], yq.z, aA2);
      aA3 = fdot2u(wq.z,             yq.z, aA3);
      aB0 = fdot2u(wv[0][4 * j + 3], yq.w, aB0);
      aB1 = fdot2u(wv[1][4 * j + 3], yq.w, aB1);
      aB2 = fdot2u(wv[2][4 * j + 3], yq.w, aB2);
      aB3 = fdot2u(wq.w,             yq.w, aB3);
    }

    // combine k-halves across the lane pair (even<->odd), all 4 gates
    float part0 = aA0 + aB0, part1 = aA1 + aB1;
    float part2 = aA2 + aB2, part3 = aA3 + aB3;
    float raw0 = part0 + __shfl_xor(part0, 1) + cx[0] + rbv[0];
    float raw1 = part1 + __shfl_xor(part1, 1) + cx[1] + rbv[1];
    float raw2 = part2 + __shfl_xor(part2, 1) + cx[2] + rbv[2];
    float raw3 = part3 + __shfl_xor(part3, 1) + cx[3] + rbv[3];

    // state update (redundant in both lanes of the pair)
    float iv = raw0, fv = raw1, zv = raw2, ov = raw3;
    float ea = __expf(-fabsf(fv));
    float ls = fminf(fv, 0.f) - __logf(1.f + ea);      // log_sigmoid(fv)
    float lfm = m + ls;
    float mn = fmaxf(iv, lfm);
    float ig = __expf(iv - mn);
    float fg = __expf(lfm - mn);
    float pz = __expf(-2.f * fabsf(zv));
    float tmag = __fdividef(1.f - pz, 1.f + pz);
    float th = (zv < 0.f) ? -tmag : tmag;              // tanh(zv)
    c = fg * c + ig * th;
    n = fg * n + ig;
    float og = __fdividef(1.f, 1.f + __expf(-ov));     // sigmoid(ov)
    float y = og * __fdividef(c, n);
    m = mn;

    if (par == 0) {
      out[out_base + (size_t)st * EE] = y;
      ypub[(cur ^ 1) * 256 + d] = __float2half(y);
    }
    __syncthreads();
    cur ^= 1;
    pg = pn;
#pragma unroll
    for (int g = 0; g < 4; ++g) cx[g] = __half2float(nx[g]);
  }
}

// ---------------------------------------------------------------------------
// GroupNorm over DH per (b,s,h), in place on out. One wave = one head.
// ---------------------------------------------------------------------------
__global__ __launch_bounds__(256) void groupnorm(
    float* __restrict__ y, const float* __restrict__ gnw)
{
  const int row = blockIdx.x;
  const int t = threadIdx.x;
  float4 v = ((const float4*)y)[(size_t)row * 256 + t];
  float s = v.x + v.y + v.z + v.w;
  float q = v.x * v.x + v.y * v.y + v.z * v.z + v.w * v.w;
#pragma unroll
  for (int mask = 1; mask < 64; mask <<= 1) {
    s += __shfl_xor(s, mask, 64);
    q += __shfl_xor(q, mask, 64);
  }
  float mu = s * (1.f / 256.f);
  float var = q * (1.f / 256.f) - mu * mu;
  float rs = rsqrtf(var + 1e-5f);
  float4 g = ((const float4*)gnw)[t];
  float4 o;
  o.x = (v.x - mu) * rs * g.x;
  o.y = (v.y - mu) * rs * g.y;
  o.z = (v.z - mu) * rs * g.z;
  o.w = (v.w - mu) * rs * g.w;
  ((float4*)y)[(size_t)row * 256 + t] = o;
}

extern "C" void kernel_launch(void* const* d_in, const int* in_sizes, int n_in,
                              void* d_out, int out_size, void* d_ws, size_t ws_size,
                              hipStream_t stream) {
  const float* x      = (const float*)d_in[0];
  const float* conv_w = (const float*)d_in[1];
  const float* conv_b = (const float*)d_in[2];
  const float* fgw    = (const float*)d_in[3];
  const float* igw    = (const float*)d_in[4];
  const float* zgw    = (const float*)d_in[5];
  const float* ogw    = (const float*)d_in[6];
  const float* rk     = (const float*)d_in[7];
  const float* rb     = (const float*)d_in[8];
  const float* gnw    = (const float*)d_in[9];
  float* out = (float*)d_out;
  __half* gx = (__half*)d_ws;   // [S][B][NH][1024] f16 = 134217728 B

  dim3 g1(256, 8, 8);
  gates_gemm<<<g1, 256, 0, stream>>>(x, conv_w, conv_b, fgw, igw, zgw, ogw, gx);

  const int scan_lds = 131072 + 1024;
  (void)hipFuncSetAttribute(reinterpret_cast<const void*>(slstm_scan),
                            hipFuncAttributeMaxDynamicSharedMemorySize, scan_lds);
  slstm_scan<<<32, 512, scan_lds, stream>>>(rk, rb, gx, out);

  groupnorm<<<BB * SS, 256, 0, stream>>>(out, gnw);
}